// Round 11
// baseline (190.905 us; speedup 1.0000x reference)
//
#include <hip/hip_runtime.h>
#include <math.h>

typedef __attribute__((ext_vector_type(8))) _Float16 half8;     // 8 fp16 (4 VGPR)
typedef __attribute__((ext_vector_type(4))) _Float16 half4;     // 4 fp16 (2 VGPR)
typedef __attribute__((ext_vector_type(4))) float f32x4;

namespace {
constexpr int T_ = 2048, DH_ = 64;
constexpr int M_ = 4096;          // B*T
constexpr int KD = 1024;          // fp16 row stride
}

// ---------------------------------------------------------------------------
// fp32 -> fp16 convert. 8 elements/thread. blockIdx.y selects source (for the
// four weight matrices stacked into one [4096][1024] fp16 buffer).
// ---------------------------------------------------------------------------
__global__ __launch_bounds__(256)
void conv_half4(const float* __restrict__ s0, const float* __restrict__ s1,
                const float* __restrict__ s2, const float* __restrict__ s3,
                _Float16* __restrict__ dst)
{
    const float* s = (blockIdx.y == 0) ? s0 : (blockIdx.y == 1) ? s1
                   : (blockIdx.y == 2) ? s2 : s3;
    const size_t i = ((size_t)blockIdx.x * 256 + threadIdx.x) * 8;
    const float4 a = *reinterpret_cast<const float4*>(s + i);
    const float4 b = *reinterpret_cast<const float4*>(s + i + 4);
    half8 h;
    h[0] = (_Float16)a.x; h[1] = (_Float16)a.y; h[2] = (_Float16)a.z; h[3] = (_Float16)a.w;
    h[4] = (_Float16)b.x; h[5] = (_Float16)b.y; h[6] = (_Float16)b.z; h[7] = (_Float16)b.w;
    *reinterpret_cast<half8*>(dst + (size_t)blockIdx.y * 1048576 + i) = h;
}

// ---------------------------------------------------------------------------
// fp16 GEMM: C = A @ W^T.  (unchanged from R9)
// ---------------------------------------------------------------------------
template <int BN>
__global__ __launch_bounds__(256)
void gemm_half(const _Float16* __restrict__ A, const _Float16* __restrict__ Bw,
               float* __restrict__ Cout,
               _Float16* __restrict__ qh, _Float16* __restrict__ kh,
               _Float16* __restrict__ vh, const int mode)
{
    constexpr int NF = BN / 32;         // col frags per wave (2 or 4)
    __shared__ _Float16 As[128 * 64];   // 16 KB
    __shared__ _Float16 Bs[BN * 64];    // 8 or 16 KB
    const int tid = threadIdx.x;
    const int l   = tid & 63;
    const int w   = tid >> 6;
    const int wm  = w >> 1, wn = w & 1;
    const int m0  = blockIdx.y * 128;
    const int n0  = blockIdx.x * BN;

    f32x4 acc[4][NF];
#pragma unroll
    for (int i = 0; i < 4; ++i)
#pragma unroll
        for (int j = 0; j < NF; ++j) acc[i][j] = (f32x4){0.f, 0.f, 0.f, 0.f};

    const int srow = l >> 3;                       // row within instr (0..7)
    const int scol = ((l & 7) ^ srow) << 3;        // pre-swizzled elem col
    const int frow = l & 15;
    const int fkb  = (l >> 4) << 4;                // byte k-offset in 32-elem step

    for (int kt = 0; kt < 16; ++kt) {
        const int kOff = kt << 6;
#pragma unroll
        for (int s = 0; s < 4; ++s) {              // A tile: 16 instrs, 4/wave
            const int j = (w << 2) + s;
            const _Float16* gp = A + (size_t)(m0 + (j << 3) + srow) * KD + kOff + scol;
            __builtin_amdgcn_global_load_lds(
                (const __attribute__((address_space(1))) void*)gp,
                (__attribute__((address_space(3))) void*)(As + (j << 9)), 16, 0, 0);
        }
#pragma unroll
        for (int s = 0; s < BN / 32; ++s) {        // B tile: BN/8 instrs
            const int j = w * (BN / 32) + s;
            const _Float16* gp = Bw + (size_t)(n0 + (j << 3) + srow) * KD + kOff + scol;
            __builtin_amdgcn_global_load_lds(
                (const __attribute__((address_space(1))) void*)gp,
                (__attribute__((address_space(3))) void*)(Bs + (j << 9)), 16, 0, 0);
        }
        __syncthreads();   // compiler drains vmcnt before barrier
#pragma unroll
        for (int ks = 0; ks < 2; ++ks) {
            half8 af[4], bfr[NF];
#pragma unroll
            for (int fi = 0; fi < 4; ++fi) {
                const int row = wm * 64 + fi * 16 + frow;
                const int cb  = (ks * 64 + fkb) ^ ((row & 7) << 4);
                af[fi] = *reinterpret_cast<const half8*>(
                    reinterpret_cast<const char*>(As) + row * 128 + cb);
            }
#pragma unroll
            for (int fj = 0; fj < NF; ++fj) {
                const int row = wn * (NF * 16) + fj * 16 + frow;
                const int cb  = (ks * 64 + fkb) ^ ((row & 7) << 4);
                bfr[fj] = *reinterpret_cast<const half8*>(
                    reinterpret_cast<const char*>(Bs) + row * 128 + cb);
            }
#pragma unroll
            for (int fi = 0; fi < 4; ++fi)
#pragma unroll
                for (int fj = 0; fj < NF; ++fj)
                    acc[fi][fj] = __builtin_amdgcn_mfma_f32_16x16x32_f16(
                        af[fi], bfr[fj], acc[fi][fj], 0, 0, 0);
        }
        __syncthreads();
    }

    const int r0 = (l >> 4) << 2;
    const float QSC = 0.125f * 1.44269504f;        // fold 1/sqrt(DH) * log2(e)
#pragma unroll
    for (int fi = 0; fi < 4; ++fi)
#pragma unroll
        for (int fj = 0; fj < NF; ++fj)
#pragma unroll
            for (int r = 0; r < 4; ++r) {
                const int m = m0 + wm * 64 + fi * 16 + r0 + r;
                const int n = n0 + wn * (NF * 16) + fj * 16 + (l & 15);
                const float vv = acc[fi][fj][r];
                if (mode == 0) {
                    const int bb = m >> 11, t = m & 2047;
                    const int which = n >> 10, nl = n & 1023;
                    const int hh = nl >> 6, dh = nl & 63;
                    const int bh = (bb << 4) + hh;
                    if (which == 0)         // q, pre-scaled for exp2-softmax
                        qh[(((size_t)bh << 11) + t) * 64 + dh] = (_Float16)(vv * QSC);
                    else if (which == 1)
                        kh[(((size_t)bh << 11) + t) * 64 + dh] = (_Float16)vv;
                    else                    // v, transposed [bh][dh][t]
                        vh[(((size_t)bh << 6) + dh) * 2048 + t] = (_Float16)vv;
                } else {
                    Cout[(size_t)m * 1024 + n] = vv;
                }
            }
}

// ---------------------------------------------------------------------------
// Flash attention, KEY-SPLIT waves + register-resident P.
// R9 was LDS-pipe-bound (~40 of 68 us: every wave re-read full K+V tiles + P
// round-trip). Now: 4 waves split the 64-key tile (16 keys each), each wave
// covers ALL 64 q of the block -> each staged K/V byte is read once.
// Swapped QK^T (mfma32(kf, qf_c)) leaves lane (c16,g4) with P[q=c16+16c]
// [keys 16w+4g4+{0..3}] -- exactly the A-operand layout of 16x16x16 MFMA
// (row=l&15, k=4*(l>>4)+j), so PV consumes P straight from registers.
// l = f32 per-lane partial sums.  O/l are per-wave partials over the wave's
// keys -> one-time cross-wave LDS tree reduction at the end (reuses K/V LDS).
// P = 2^(min(s,15.9)), q pre-scaled by 0.125*log2e (exact softmax, see R6).
// LDS 32 KB dynamic; __launch_bounds__(256,4) targets <=128 VGPR.
// ---------------------------------------------------------------------------
#define SWZ(row, bytecol) (((row) << 7) + ((bytecol) ^ (((row) & 7) << 4)))

__global__ __launch_bounds__(256, 4)
void attn_mfma(const _Float16* __restrict__ Qh, const _Float16* __restrict__ Kh,
               const _Float16* __restrict__ Vh, _Float16* __restrict__ Yh)
{
    extern __shared__ char smem[];      // 32 KB: Ks[2] 16K | Vs[2] 16K
    _Float16* KsB = (_Float16*)smem;            // [2][64*64]
    _Float16* VsB = (_Float16*)(smem + 16384);  // [2][64*64]  [d][key]
    // post-loop reduction overlay (K/V dead by then):
    float* linv  = (float*)smem;                 // [64]
    float* lpart = (float*)(smem + 256);         // [16][68]
    float* areas = (float*)(smem + 4608);        // 3 x [64][34] f32 (26112 B)

    const int tid = threadIdx.x;
    const int l   = tid & 63;
    const int w   = tid >> 6;          // = key-slice index
    const int g4  = l >> 4;
    const int c16 = l & 15;
    const int bh  = blockIdx.y;
    const int t0  = blockIdx.x * 64;
    const size_t qkbase = (size_t)bh * T_ * DH_;
    const size_t vbase  = (size_t)bh * DH_ * T_;

    const int srow = l >> 3;
    const int scol = ((l & 7) ^ srow) << 3;      // pre-swizzled source col

    // Q fragments (B-operand of swapped QK^T): rows q = 16c + c16, in regs.
    half8 qf[4][2];
#pragma unroll
    for (int c = 0; c < 4; ++c)
#pragma unroll
        for (int ks = 0; ks < 2; ++ks)
            qf[c][ks] = *reinterpret_cast<const half8*>(
                Qh + qkbase + (size_t)(t0 + 16 * c + c16) * 64 + ks * 32 + g4 * 8);

    // stage K/V tile 0 -> buffer 0
#pragma unroll
    for (int s = 0; s < 2; ++s) {
        const int j   = (w << 1) + s;
        const int row = (j << 3) + srow;
        const _Float16* gk = Kh + qkbase + (size_t)row * 64 + scol;
        __builtin_amdgcn_global_load_lds(
            (const __attribute__((address_space(1))) void*)gk,
            (__attribute__((address_space(3))) void*)(KsB + (j << 9)), 16, 0, 0);
        const _Float16* gv = Vh + vbase + (size_t)row * T_ + scol;
        __builtin_amdgcn_global_load_lds(
            (const __attribute__((address_space(1))) void*)gv,
            (__attribute__((address_space(3))) void*)(VsB + (j << 9)), 16, 0, 0);
    }
    __syncthreads();

    f32x4 o[4][4];                     // [qc][dd]: q=16c+4g4+r, d=16dd+c16
    float lsum[4] = {0.f, 0.f, 0.f, 0.f};
#pragma unroll
    for (int c = 0; c < 4; ++c)
#pragma unroll
        for (int dd = 0; dd < 4; ++dd) o[c][dd] = (f32x4){0.f, 0.f, 0.f, 0.f};

    // vf swizzle pieces (dd-invariant): keys = 16w + 4g4 + {0..3}
    const int vblk = (2 * w + (g4 >> 1));        // 16B-block of key*2 bytes
    const int vsub = (g4 & 1) << 3;              // 8B half

    for (int ktile = 0; ktile < T_ / 64; ++ktile) {
        const int cur = ktile & 1;
        if (ktile + 1 < T_ / 64) {     // issue next tile -> other buffer
            const int nxt = cur ^ 1;
#pragma unroll
            for (int s = 0; s < 2; ++s) {
                const int j   = (w << 1) + s;
                const int row = (j << 3) + srow;
                const _Float16* gk = Kh + qkbase +
                    (size_t)((ktile + 1) * 64 + row) * 64 + scol;
                __builtin_amdgcn_global_load_lds(
                    (const __attribute__((address_space(1))) void*)gk,
                    (__attribute__((address_space(3))) void*)(KsB + nxt * 4096 + (j << 9)), 16, 0, 0);
                const _Float16* gv = Vh + vbase + (size_t)row * T_ +
                    (ktile + 1) * 64 + scol;
                __builtin_amdgcn_global_load_lds(
                    (const __attribute__((address_space(1))) void*)gv,
                    (__attribute__((address_space(3))) void*)(VsB + nxt * 4096 + (j << 9)), 16, 0, 0);
            }
        }

        const char* ksB = reinterpret_cast<const char*>(KsB + cur * 4096);
        const char* vsB = reinterpret_cast<const char*>(VsB + cur * 4096);

        // S^T = K Q^T over this wave's 16 keys (rows key=16w+c16)
        f32x4 s[4];
#pragma unroll
        for (int c = 0; c < 4; ++c) s[c] = (f32x4){0.f, 0.f, 0.f, 0.f};
        __builtin_amdgcn_s_setprio(1);
#pragma unroll
        for (int ks = 0; ks < 2; ++ks) {
            const int key = w * 16 + c16;
            const half8 kf = *reinterpret_cast<const half8*>(
                ksB + SWZ(key, ks * 64 + (g4 << 4)));
#pragma unroll
            for (int c = 0; c < 4; ++c)
                s[c] = __builtin_amdgcn_mfma_f32_16x16x32_f16(kf, qf[c][ks], s[c], 0, 0, 0);
        }
        __builtin_amdgcn_s_setprio(0);

        // P = 2^s in registers (lane: q=16c+c16, keys 16w+4g4+{0..3});
        // f32 partial row-sums for l; cast to half4 = PV A-fragment.
        half4 pf[4];
#pragma unroll
        for (int c = 0; c < 4; ++c) {
            const float p0 = __builtin_amdgcn_exp2f(fminf(s[c][0], 15.9f));
            const float p1 = __builtin_amdgcn_exp2f(fminf(s[c][1], 15.9f));
            const float p2 = __builtin_amdgcn_exp2f(fminf(s[c][2], 15.9f));
            const float p3 = __builtin_amdgcn_exp2f(fminf(s[c][3], 15.9f));
            lsum[c] += (p0 + p1) + (p2 + p3);
            const auto a = __builtin_amdgcn_cvt_pkrtz(p0, p1);   // __fp16 x2
            const auto b = __builtin_amdgcn_cvt_pkrtz(p2, p3);
            pf[c][0] = (_Float16)a[0]; pf[c][1] = (_Float16)a[1];
            pf[c][2] = (_Float16)b[0]; pf[c][3] = (_Float16)b[1];
        }

        // O += P V over this wave's keys (x16 MFMA, P from regs)
        __builtin_amdgcn_s_setprio(1);
#pragma unroll
        for (int dd = 0; dd < 4; ++dd) {
            const int d = 16 * dd + c16;
            const half4 vf = *reinterpret_cast<const half4*>(
                vsB + d * 128 + (((vblk) ^ (d & 7)) << 4) + vsub);
#pragma unroll
            for (int c = 0; c < 4; ++c)
                o[c][dd] = __builtin_amdgcn_mfma_f32_16x16x16f16(pf[c], vf, o[c][dd], 0, 0, 0);
        }
        __builtin_amdgcn_s_setprio(0);

        __syncthreads();   // next tile staged; all waves done with buf cur
    }

    // ---- cross-wave reduction (once; reuses K/V LDS) ----
    // l partials: index q = 16c + c16, slice = (w,g4)
#pragma unroll
    for (int c = 0; c < 4; ++c)
        lpart[(w * 4 + g4) * 68 + 16 * c + c16] = lsum[c];
    __syncthreads();
    if (w == 0) {
        float t = 0.f;
#pragma unroll
        for (int i = 0; i < 16; ++i) t += lpart[i * 68 + l];
        linv[l] = 1.f / t;
    }
    __syncthreads();

    const int bb = bh >> 4, hh = bh & 15;
    float li[4][4];
    if (w == 0) {
#pragma unroll
        for (int c = 0; c < 4; ++c)
#pragma unroll
            for (int r = 0; r < 4; ++r)
                li[c][r] = linv[16 * c + 4 * g4 + r];
    }

#pragma unroll
    for (int h2 = 0; h2 < 2; ++h2) {   // two d-halves of 32 cols
        if (w > 0) {
            float* A = areas + (w - 1) * 2176;   // [64][34]
#pragma unroll
            for (int c = 0; c < 4; ++c)
#pragma unroll
                for (int dd2 = 0; dd2 < 2; ++dd2) {
                    const int dd = h2 * 2 + dd2;
#pragma unroll
                    for (int r = 0; r < 4; ++r)
                        A[(16 * c + 4 * g4 + r) * 34 + 16 * dd2 + c16] = o[c][dd][r];
                }
        }
        __syncthreads();
        if (w == 0) {
#pragma unroll
            for (int c = 0; c < 4; ++c)
#pragma unroll
                for (int dd2 = 0; dd2 < 2; ++dd2) {
                    const int dd = h2 * 2 + dd2;
#pragma unroll
                    for (int r = 0; r < 4; ++r) {
                        const int qi = 16 * c + 4 * g4 + r;
                        float v = o[c][dd][r]
                                + areas[qi * 34 + 16 * dd2 + c16]
                                + areas[2176 + qi * 34 + 16 * dd2 + c16]
                                + areas[4352 + qi * 34 + 16 * dd2 + c16];
                        v *= li[c][r];
                        const int t = t0 + qi;
                        Yh[((size_t)bb * T_ + t) * 1024 + hh * 64 + h2 * 32
                           + 16 * dd2 + c16] = (_Float16)v;
                    }
                }
        }
        __syncthreads();
    }
}

// ---------------------------------------------------------------------------
extern "C" void kernel_launch(void* const* d_in, const int* in_sizes, int n_in,
                              void* d_out, int out_size, void* d_ws, size_t ws_size,
                              hipStream_t stream)
{
    const float* x  = (const float*)d_in[0];
    const float* Wq = (const float*)d_in[1];
    const float* Wk = (const float*)d_in[2];
    const float* Wv = (const float*)d_in[3];
    const float* Wo = (const float*)d_in[4];

    // workspace layout (all fp16, BYTE offsets; each buffer is 8 MB):
    //   xh [4096][1024]    @ 0
    //   wh [4096][1024]    @  8 MB (Wq|Wk|Wv|Wo rows)
    //   qh [32][2048][64]  @ 16 MB
    //   kh [32][2048][64]  @ 24 MB
    //   vh [32][64][2048]  @ 32 MB
    unsigned char* ws = (unsigned char*)d_ws;
    _Float16* xh = (_Float16*)ws;
    _Float16* wh = (_Float16*)(ws + (size_t) 8388608);
    _Float16* qh = (_Float16*)(ws + (size_t)16777216);
    _Float16* kh = (_Float16*)(ws + (size_t)25165824);
    _Float16* vh = (_Float16*)(ws + (size_t)33554432);
    _Float16* yh = xh;   // xh dead after QKV GEMM; attn output aliases it

    conv_half4<<<dim3(2048, 1), 256, 0, stream>>>(x, nullptr, nullptr, nullptr, xh);
    conv_half4<<<dim3(512, 4), 256, 0, stream>>>(Wq, Wk, Wv, Wo, wh);

    dim3 blk(256);
    dim3 g1(24, 32);   // N=3072, 128-col tiles: fused QKV projection (3 blk/CU)
    gemm_half<128><<<g1, blk, 0, stream>>>(xh, wh, nullptr, qh, kh, vh, 0);

    dim3 ga(T_ / 64, 32);   // 1024 blocks = 4/CU
    attn_mfma<<<ga, blk, 32768, stream>>>(qh, kh, vh, yh);

    dim3 g2(16, 32);   // N=1024, 64-col tiles: 512 blocks = 2/CU
    gemm_half<64><<<g2, blk, 0, stream>>>(yh, wh + (size_t)3072 * KD, (float*)d_out,
                                          nullptr, nullptr, nullptr, 1);
}

// Round 12
// 154.527 us; speedup vs baseline: 1.2354x; 1.2354x over previous
//
#include <hip/hip_runtime.h>
#include <math.h>

typedef __attribute__((ext_vector_type(8))) _Float16 half8;     // 8 fp16 (4 VGPR)
typedef __attribute__((ext_vector_type(4))) _Float16 half4;     // 4 fp16 (2 VGPR)
typedef __attribute__((ext_vector_type(4))) float f32x4;

namespace {
constexpr int T_ = 2048, DH_ = 64;
constexpr int M_ = 4096;          // B*T
constexpr int KD = 1024;          // fp16 row stride
}

// ---------------------------------------------------------------------------
// fp32 -> fp16 convert. 8 elements/thread. blockIdx.y selects source (for the
// four weight matrices stacked into one [4096][1024] fp16 buffer).
// ---------------------------------------------------------------------------
__global__ __launch_bounds__(256)
void conv_half4(const float* __restrict__ s0, const float* __restrict__ s1,
                const float* __restrict__ s2, const float* __restrict__ s3,
                _Float16* __restrict__ dst)
{
    const float* s = (blockIdx.y == 0) ? s0 : (blockIdx.y == 1) ? s1
                   : (blockIdx.y == 2) ? s2 : s3;
    const size_t i = ((size_t)blockIdx.x * 256 + threadIdx.x) * 8;
    const float4 a = *reinterpret_cast<const float4*>(s + i);
    const float4 b = *reinterpret_cast<const float4*>(s + i + 4);
    half8 h;
    h[0] = (_Float16)a.x; h[1] = (_Float16)a.y; h[2] = (_Float16)a.z; h[3] = (_Float16)a.w;
    h[4] = (_Float16)b.x; h[5] = (_Float16)b.y; h[6] = (_Float16)b.z; h[7] = (_Float16)b.w;
    *reinterpret_cast<half8*>(dst + (size_t)blockIdx.y * 1048576 + i) = h;
}

// ---------------------------------------------------------------------------
// fp16 GEMM: C = A @ W^T.  (unchanged from R9)
// ---------------------------------------------------------------------------
template <int BN>
__global__ __launch_bounds__(256)
void gemm_half(const _Float16* __restrict__ A, const _Float16* __restrict__ Bw,
               float* __restrict__ Cout,
               _Float16* __restrict__ qh, _Float16* __restrict__ kh,
               _Float16* __restrict__ vh, const int mode)
{
    constexpr int NF = BN / 32;         // col frags per wave (2 or 4)
    __shared__ _Float16 As[128 * 64];   // 16 KB
    __shared__ _Float16 Bs[BN * 64];    // 8 or 16 KB
    const int tid = threadIdx.x;
    const int l   = tid & 63;
    const int w   = tid >> 6;
    const int wm  = w >> 1, wn = w & 1;
    const int m0  = blockIdx.y * 128;
    const int n0  = blockIdx.x * BN;

    f32x4 acc[4][NF];
#pragma unroll
    for (int i = 0; i < 4; ++i)
#pragma unroll
        for (int j = 0; j < NF; ++j) acc[i][j] = (f32x4){0.f, 0.f, 0.f, 0.f};

    const int srow = l >> 3;                       // row within instr (0..7)
    const int scol = ((l & 7) ^ srow) << 3;        // pre-swizzled elem col
    const int frow = l & 15;
    const int fkb  = (l >> 4) << 4;                // byte k-offset in 32-elem step

    for (int kt = 0; kt < 16; ++kt) {
        const int kOff = kt << 6;
#pragma unroll
        for (int s = 0; s < 4; ++s) {              // A tile: 16 instrs, 4/wave
            const int j = (w << 2) + s;
            const _Float16* gp = A + (size_t)(m0 + (j << 3) + srow) * KD + kOff + scol;
            __builtin_amdgcn_global_load_lds(
                (const __attribute__((address_space(1))) void*)gp,
                (__attribute__((address_space(3))) void*)(As + (j << 9)), 16, 0, 0);
        }
#pragma unroll
        for (int s = 0; s < BN / 32; ++s) {        // B tile: BN/8 instrs
            const int j = w * (BN / 32) + s;
            const _Float16* gp = Bw + (size_t)(n0 + (j << 3) + srow) * KD + kOff + scol;
            __builtin_amdgcn_global_load_lds(
                (const __attribute__((address_space(1))) void*)gp,
                (__attribute__((address_space(3))) void*)(Bs + (j << 9)), 16, 0, 0);
        }
        __syncthreads();   // compiler drains vmcnt before barrier
#pragma unroll
        for (int ks = 0; ks < 2; ++ks) {
            half8 af[4], bfr[NF];
#pragma unroll
            for (int fi = 0; fi < 4; ++fi) {
                const int row = wm * 64 + fi * 16 + frow;
                const int cb  = (ks * 64 + fkb) ^ ((row & 7) << 4);
                af[fi] = *reinterpret_cast<const half8*>(
                    reinterpret_cast<const char*>(As) + row * 128 + cb);
            }
#pragma unroll
            for (int fj = 0; fj < NF; ++fj) {
                const int row = wn * (NF * 16) + fj * 16 + frow;
                const int cb  = (ks * 64 + fkb) ^ ((row & 7) << 4);
                bfr[fj] = *reinterpret_cast<const half8*>(
                    reinterpret_cast<const char*>(Bs) + row * 128 + cb);
            }
#pragma unroll
            for (int fi = 0; fi < 4; ++fi)
#pragma unroll
                for (int fj = 0; fj < NF; ++fj)
                    acc[fi][fj] = __builtin_amdgcn_mfma_f32_16x16x32_f16(
                        af[fi], bfr[fj], acc[fi][fj], 0, 0, 0);
        }
        __syncthreads();
    }

    const int r0 = (l >> 4) << 2;
    const float QSC = 0.125f * 1.44269504f;        // fold 1/sqrt(DH) * log2(e)
#pragma unroll
    for (int fi = 0; fi < 4; ++fi)
#pragma unroll
        for (int fj = 0; fj < NF; ++fj)
#pragma unroll
            for (int r = 0; r < 4; ++r) {
                const int m = m0 + wm * 64 + fi * 16 + r0 + r;
                const int n = n0 + wn * (NF * 16) + fj * 16 + (l & 15);
                const float vv = acc[fi][fj][r];
                if (mode == 0) {
                    const int bb = m >> 11, t = m & 2047;
                    const int which = n >> 10, nl = n & 1023;
                    const int hh = nl >> 6, dh = nl & 63;
                    const int bh = (bb << 4) + hh;
                    if (which == 0)         // q, pre-scaled for exp2-softmax
                        qh[(((size_t)bh << 11) + t) * 64 + dh] = (_Float16)(vv * QSC);
                    else if (which == 1)
                        kh[(((size_t)bh << 11) + t) * 64 + dh] = (_Float16)vv;
                    else                    // v, transposed [bh][dh][t]
                        vh[(((size_t)bh << 6) + dh) * 2048 + t] = (_Float16)vv;
                } else {
                    Cout[(size_t)m * 1024 + n] = vv;
                }
            }
}

// ---------------------------------------------------------------------------
// Flash attention, HYBRID 2q x 2k wave split + register-resident P.
// R11 (full 4-way key split) was correct but spilled: o[4][4]=64 VGPR + qf=16
// vs the 64-VGPR allocation -> scratch round-trips (WRITE 32 MB, FETCH +31 MB).
// Now waves (wq,wk): 32 q-rows x 32 keys each -> o[2][4]=32 VGPR, peak ~90.
// Each K/V byte read by 2 waves (vs 4 in R9): LDS traffic still halved.
// Swapped QK^T (verified R9/R11): lane (c16,g4) gets S[key=32wk+16kc+4g4+r]
// [q=32wq+16c+c16]; pf[kc][c] is exactly the 16x16x16 A-fragment, so PV runs
// P straight from registers.  l = f32 per-lane partials.
// Epilogue: 8-slice l-reduce + 2-way O merge via LDS overlay (wk=1 writes,
// wk=0 adds+normalizes+stores).  Static 32 KB LDS (dbuf K/V; overlay reuses).
// P = 2^(min(s,15.9)), q pre-scaled by 0.125*log2e (exact softmax, see R6).
// ---------------------------------------------------------------------------
#define SWZ(row, bytecol) (((row) << 7) + ((bytecol) ^ (((row) & 7) << 4)))

__global__ __launch_bounds__(256)
void attn_mfma(const _Float16* __restrict__ Qh, const _Float16* __restrict__ Kh,
               const _Float16* __restrict__ Vh, _Float16* __restrict__ Yh)
{
    __shared__ uint4 smem4[2048];                 // 32 KB, 16B-aligned
    char* smem = (char*)smem4;
    _Float16* KsB = (_Float16*)smem;              // [2][64*64]  16 KB
    _Float16* VsB = (_Float16*)(smem + 16384);    // [2][64*64]  16 KB  [d][key]
    // post-loop overlay (K/V dead):
    float* linv  = (float*)smem;                  // [64]            256 B
    float* lpart = (float*)(smem + 256);          // [8][68]        2176 B
    float* oxch  = (float*)(smem + 2432);         // [2][32][65]   16640 B

    const int tid = threadIdx.x;
    const int l   = tid & 63;
    const int w   = tid >> 6;
    const int wq  = w >> 1;            // q-half
    const int wk  = w & 1;             // key-half
    const int g4  = l >> 4;
    const int c16 = l & 15;
    const int bh  = blockIdx.y;
    const int t0  = blockIdx.x * 64;
    const size_t qkbase = (size_t)bh * T_ * DH_;
    const size_t vbase  = (size_t)bh * DH_ * T_;

    const int srow = l >> 3;
    const int scol = ((l & 7) ^ srow) << 3;      // pre-swizzled source col

    // Q fragments (B-operand of swapped QK^T): rows q = 32wq + 16c + c16.
    half8 qf[2][2];
#pragma unroll
    for (int c = 0; c < 2; ++c)
#pragma unroll
        for (int ks = 0; ks < 2; ++ks)
            qf[c][ks] = *reinterpret_cast<const half8*>(
                Qh + qkbase + (size_t)(t0 + 32 * wq + 16 * c + c16) * 64
                    + ks * 32 + g4 * 8);

    // stage K/V tile 0 -> buffer 0 (8 instrs each across 4 waves)
#pragma unroll
    for (int s = 0; s < 2; ++s) {
        const int j   = (w << 1) + s;
        const int row = (j << 3) + srow;
        const _Float16* gk = Kh + qkbase + (size_t)row * 64 + scol;
        __builtin_amdgcn_global_load_lds(
            (const __attribute__((address_space(1))) void*)gk,
            (__attribute__((address_space(3))) void*)(KsB + (j << 9)), 16, 0, 0);
        const _Float16* gv = Vh + vbase + (size_t)row * T_ + scol;
        __builtin_amdgcn_global_load_lds(
            (const __attribute__((address_space(1))) void*)gv,
            (__attribute__((address_space(3))) void*)(VsB + (j << 9)), 16, 0, 0);
    }
    __syncthreads();

    f32x4 o[2][4];                     // [c][dd]: q=32wq+16c+4g4+r, d=16dd+c16
    float lsum[2] = {0.f, 0.f};
#pragma unroll
    for (int c = 0; c < 2; ++c)
#pragma unroll
        for (int dd = 0; dd < 4; ++dd) o[c][dd] = (f32x4){0.f, 0.f, 0.f, 0.f};

    for (int ktile = 0; ktile < T_ / 64; ++ktile) {
        const int cur = ktile & 1;
        if (ktile + 1 < T_ / 64) {     // issue next tile -> other buffer
            const int nxt = cur ^ 1;
#pragma unroll
            for (int s = 0; s < 2; ++s) {
                const int j   = (w << 1) + s;
                const int row = (j << 3) + srow;
                const _Float16* gk = Kh + qkbase +
                    (size_t)((ktile + 1) * 64 + row) * 64 + scol;
                __builtin_amdgcn_global_load_lds(
                    (const __attribute__((address_space(1))) void*)gk,
                    (__attribute__((address_space(3))) void*)(KsB + nxt * 4096 + (j << 9)), 16, 0, 0);
                const _Float16* gv = Vh + vbase + (size_t)row * T_ +
                    (ktile + 1) * 64 + scol;
                __builtin_amdgcn_global_load_lds(
                    (const __attribute__((address_space(1))) void*)gv,
                    (__attribute__((address_space(3))) void*)(VsB + nxt * 4096 + (j << 9)), 16, 0, 0);
            }
        }

        const char* ksB = reinterpret_cast<const char*>(KsB + cur * 4096);
        const char* vsB = reinterpret_cast<const char*>(VsB + cur * 4096);

        // S^T = K Q^T over this wave's 32 keys (2 chunks of 16)
        f32x4 s[2][2];
#pragma unroll
        for (int kc = 0; kc < 2; ++kc)
#pragma unroll
            for (int c = 0; c < 2; ++c) s[kc][c] = (f32x4){0.f, 0.f, 0.f, 0.f};
        __builtin_amdgcn_s_setprio(1);
#pragma unroll
        for (int ks = 0; ks < 2; ++ks)
#pragma unroll
            for (int kc = 0; kc < 2; ++kc) {
                const int key = 32 * wk + 16 * kc + c16;
                const half8 kf = *reinterpret_cast<const half8*>(
                    ksB + SWZ(key, ks * 64 + (g4 << 4)));
#pragma unroll
                for (int c = 0; c < 2; ++c)
                    s[kc][c] = __builtin_amdgcn_mfma_f32_16x16x32_f16(
                        kf, qf[c][ks], s[kc][c], 0, 0, 0);
            }
        __builtin_amdgcn_s_setprio(0);

        // P = 2^s in registers; f32 partial row-sums; cast to PV A-fragments.
        half4 pf[2][2];
#pragma unroll
        for (int kc = 0; kc < 2; ++kc)
#pragma unroll
            for (int c = 0; c < 2; ++c) {
                const float p0 = __builtin_amdgcn_exp2f(fminf(s[kc][c][0], 15.9f));
                const float p1 = __builtin_amdgcn_exp2f(fminf(s[kc][c][1], 15.9f));
                const float p2 = __builtin_amdgcn_exp2f(fminf(s[kc][c][2], 15.9f));
                const float p3 = __builtin_amdgcn_exp2f(fminf(s[kc][c][3], 15.9f));
                lsum[c] += (p0 + p1) + (p2 + p3);
                const auto a = __builtin_amdgcn_cvt_pkrtz(p0, p1);   // __fp16 x2
                const auto b = __builtin_amdgcn_cvt_pkrtz(p2, p3);
                pf[kc][c][0] = (_Float16)a[0]; pf[kc][c][1] = (_Float16)a[1];
                pf[kc][c][2] = (_Float16)b[0]; pf[kc][c][3] = (_Float16)b[1];
            }

        // O += P V over this wave's keys (x16 MFMA, P from regs)
        __builtin_amdgcn_s_setprio(1);
#pragma unroll
        for (int dd = 0; dd < 4; ++dd) {
            const int d = 16 * dd + c16;
#pragma unroll
            for (int kc = 0; kc < 2; ++kc) {
                const int blk = 4 * wk + 2 * kc + (g4 >> 1);
                const half4 vf = *reinterpret_cast<const half4*>(
                    vsB + d * 128 + ((blk ^ (d & 7)) << 4) + ((g4 & 1) << 3));
#pragma unroll
                for (int c = 0; c < 2; ++c)
                    o[c][dd] = __builtin_amdgcn_mfma_f32_16x16x16f16(
                        pf[kc][c], vf, o[c][dd], 0, 0, 0);
            }
        }
        __builtin_amdgcn_s_setprio(0);

        __syncthreads();   // next tile staged; all waves done with buf cur
    }

    // ---- epilogue: l-reduce (8 slices) + 2-way O merge ----
#pragma unroll
    for (int c = 0; c < 2; ++c)
        lpart[(wk * 4 + g4) * 68 + 32 * wq + 16 * c + c16] = lsum[c];
    if (wk) {
#pragma unroll
        for (int c = 0; c < 2; ++c)
#pragma unroll
            for (int dd = 0; dd < 4; ++dd)
#pragma unroll
                for (int r = 0; r < 4; ++r)
                    oxch[(wq * 32 + 16 * c + 4 * g4 + r) * 65 + 16 * dd + c16]
                        = o[c][dd][r];
    }
    __syncthreads();
    if (tid < 64) {
        float t = 0.f;
#pragma unroll
        for (int i = 0; i < 8; ++i) t += lpart[i * 68 + tid];
        linv[tid] = 1.f / t;
    }
    __syncthreads();

    if (!wk) {
        const int bb = bh >> 4, hh = bh & 15;
#pragma unroll
        for (int c = 0; c < 2; ++c) {
#pragma unroll
            for (int r = 0; r < 4; ++r) {
                const int qi = 32 * wq + 16 * c + 4 * g4 + r;
                const float li = linv[qi];
                const int t = t0 + qi;
                const size_t yrow = ((size_t)bb * T_ + t) * 1024 + hh * 64;
#pragma unroll
                for (int dd = 0; dd < 4; ++dd) {
                    const float v = (o[c][dd][r]
                        + oxch[(wq * 32 + 16 * c + 4 * g4 + r) * 65 + 16 * dd + c16]) * li;
                    Yh[yrow + 16 * dd + c16] = (_Float16)v;
                }
            }
        }
    }
}

// ---------------------------------------------------------------------------
extern "C" void kernel_launch(void* const* d_in, const int* in_sizes, int n_in,
                              void* d_out, int out_size, void* d_ws, size_t ws_size,
                              hipStream_t stream)
{
    const float* x  = (const float*)d_in[0];
    const float* Wq = (const float*)d_in[1];
    const float* Wk = (const float*)d_in[2];
    const float* Wv = (const float*)d_in[3];
    const float* Wo = (const float*)d_in[4];

    // workspace layout (all fp16, BYTE offsets; each buffer is 8 MB):
    //   xh [4096][1024]    @ 0
    //   wh [4096][1024]    @  8 MB (Wq|Wk|Wv|Wo rows)
    //   qh [32][2048][64]  @ 16 MB
    //   kh [32][2048][64]  @ 24 MB
    //   vh [32][64][2048]  @ 32 MB
    unsigned char* ws = (unsigned char*)d_ws;
    _Float16* xh = (_Float16*)ws;
    _Float16* wh = (_Float16*)(ws + (size_t) 8388608);
    _Float16* qh = (_Float16*)(ws + (size_t)16777216);
    _Float16* kh = (_Float16*)(ws + (size_t)25165824);
    _Float16* vh = (_Float16*)(ws + (size_t)33554432);
    _Float16* yh = xh;   // xh dead after QKV GEMM; attn output aliases it

    conv_half4<<<dim3(2048, 1), 256, 0, stream>>>(x, nullptr, nullptr, nullptr, xh);
    conv_half4<<<dim3(512, 4), 256, 0, stream>>>(Wq, Wk, Wv, Wo, wh);

    dim3 blk(256);
    dim3 g1(24, 32);   // N=3072, 128-col tiles: fused QKV projection (3 blk/CU)
    gemm_half<128><<<g1, blk, 0, stream>>>(xh, wh, nullptr, qh, kh, vh, 0);

    dim3 ga(T_ / 64, 32);   // 1024 blocks = 4/CU
    attn_mfma<<<ga, blk, 0, stream>>>(qh, kh, vh, yh);

    dim3 g2(16, 32);   // N=1024, 64-col tiles: 512 blocks = 2/CU
    gemm_half<64><<<g2, blk, 0, stream>>>(yh, wh + (size_t)3072 * KD, (float*)d_out,
                                          nullptr, nullptr, nullptr, 1);
}